// Round 2
// baseline (131.536 us; speedup 1.0000x reference)
//
#include <hip/hip_runtime.h>

#define NSLOT 4
#define SLOT_B 18432                       // 18 cols x 1024B (512 bf16, swizzled grouped)
#define OROW_OFF (NSLOT*SLOT_B)            // 73728
#define SMEM2 (OROW_OFF + 2*16*512*4)      // + double-buffered f32 orow = 139264

typedef __attribute__((ext_vector_type(8))) short bf16x8;
typedef __attribute__((ext_vector_type(4))) float f32x4;
typedef __attribute__((ext_vector_type(4))) unsigned int u32x4;

__device__ __forceinline__ short f2bf(float f) {
  union { float f; unsigned u; } v; v.f = f;
  unsigned r = v.u + 0x7FFFu + ((v.u >> 16) & 1u);   // RNE
  return (short)(r >> 16);
}

__device__ __forceinline__ void gld_lds16(const void* g, void* l) {
  __builtin_amdgcn_global_load_lds(
      (__attribute__((address_space(1))) void*)(g),
      (__attribute__((address_space(3))) void*)(l), 16, 0, 0);
}

// ---------------- Pass 1: permute + bf16 + swizzle-bake -> xs in d_ws ----------------
__global__ __launch_bounds__(256) void permute_kernel(
    const float* __restrict__ x, const int* __restrict__ bin,
    unsigned char* __restrict__ xs)
{
  __shared__ unsigned short pos_tab[512];
  __shared__ char stage[4][1024];
  const int t = threadIdx.x;
  { int c0 = bin[t], c1 = bin[t + 256];
    pos_tab[c0] = (unsigned short)t; pos_tab[c1] = (unsigned short)(t + 256); }
  __syncthreads();

  const int w = t >> 6, lane = t & 63;
  char* st = stage[w];
  const int pbase = blockIdx.x * 32 + w * 8;
  for (int i = 0; i < 8; ++i) {
    const int p = pbase + i;                                   // pixel = (b*64+h)*64+gcol
    const unsigned swz = (unsigned)((((p & 63) + 1) & 7) << 4);
    const float* src = x + (size_t)p * 512 + lane * 4;
    f32x4 v0 = *(const f32x4*)(src);
    f32x4 v1 = *(const f32x4*)(src + 256);
    const int cb = lane * 4;
#pragma unroll
    for (int k = 0; k < 4; ++k)
      *(short*)(st + (((unsigned)pos_tab[cb + k] * 2u) ^ swz)) = f2bf(v0[k]);
#pragma unroll
    for (int k = 0; k < 4; ++k)
      *(short*)(st + (((unsigned)pos_tab[256 + cb + k] * 2u) ^ swz)) = f2bf(v1[k]);
    asm volatile("s_waitcnt lgkmcnt(0)" ::: "memory");         // wave-local: all lanes' writes done
    u32x4 d = *(const u32x4*)(st + lane * 16);
    *(u32x4*)(xs + (size_t)p * 1024 + lane * 16) = d;
  }
}

// ---------------- Pass 2: conv via DMA-staged LDS + MFMA, 1 barrier/row ----------------
__global__ __launch_bounds__(1024, 4) void conv_kernel(
    const unsigned char* __restrict__ xs, const float* __restrict__ wts,
    const float* __restrict__ bias, const int* __restrict__ bout,
    float* __restrict__ out)
{
  extern __shared__ char smem[];
  float* orow = (float*)(smem + OROW_OFF);

  const int t = threadIdx.x;
  const int lane = t & 63;
  const int g = t >> 6;          // wave id == channel block
  const int g4 = lane >> 4;
  const int n16 = lane & 15;

  const int bid = blockIdx.x;    // 256 = 16 b * 4 strips * 4 segs
  const int b = bid >> 4;
  const int strip = (bid >> 2) & 3;
  const int seg = bid & 3;
  const int hs = seg * 16;
  const int w0 = strip * 16;

  // zero all slots once (covers w-halo cols and row -1; never re-dirtied there)
  {
    u32x4 z = {0, 0, 0, 0};
    for (int zz = t; zz < (NSLOT * SLOT_B) / 16; zz += 1024)
      *(u32x4*)(smem + zz * 16) = z;
  }

  // weight fragments (B-frag elem j <-> ci = g4*8+j, same kappa as A)
  bf16x8 wf[9][2];
  {
    const float* Wg = wts + g * (9 * 32 * 32);
#pragma unroll
    for (int tap = 0; tap < 9; ++tap)
#pragma unroll
      for (int nt = 0; nt < 2; ++nt) {
        bf16x8 f;
#pragma unroll
        for (int j = 0; j < 8; ++j)
          f[j] = f2bf(Wg[(tap * 32 + g4 * 8 + j) * 32 + nt * 16 + n16]);
        wf[tap][nt] = f;
      }
  }
  const int opos0 = bout[g * 32 + n16];
  const int opos1 = bout[g * 32 + 16 + n16];
  const int c4 = (t & 127) << 2;
  const int pixq = t >> 7;
  const f32x4 bias4 = *(const f32x4*)(bias + c4);

  auto stage_row = [&](int grow) {    // wave-distributed DMA of one 18KB row window
    if (grow < 0 || grow > 63) return;
    char* slot = smem + (grow & 3) * SLOT_B;
    const unsigned char* src = xs + ((size_t)((b * 64 + grow) * 64 + (w0 - 1)) * 1024);
    int gcol0 = w0 - 1 + g;
    if (gcol0 >= 0)                   // gcol0 <= 62 always
      gld_lds16(src + g * 1024 + lane * 16, slot + g * 1024);
    if (g < 2) {
      int c = g + 16;
      if (w0 - 1 + c < 64)
        gld_lds16(src + c * 1024 + lane * 16, slot + c * 1024);
    }
  };

  __syncthreads();                    // zeros visible before any DMA lands
  stage_row(hs - 1); stage_row(hs); stage_row(hs + 1);
  __syncthreads();                    // vmcnt(0)+lgkmcnt(0)+barrier: window ready

  const int gbase = g * 64 + g4 * 16;
  const size_t outb = (size_t)b * (64 * 64 * 512);
  const int hstage_max = (hs + 16 < 63) ? hs + 16 : 63;

  for (int h = hs; h < hs + 16; ++h) {
    // P0: prefetch row h+2 (async; drained at this iter's closing barrier)
    if (h + 2 <= hstage_max) {
      stage_row(h + 2);
    } else if (h + 2 == 64) {        // bottom halo: re-zero slot 0 (held row 60)
      u32x4 z = {0, 0, 0, 0};
      *(u32x4*)(smem + t * 16) = z;
      if (t < 128) *(u32x4*)(smem + 16384 + t * 16) = z;
    }

    // P3 (early): flush row h-1 from the other orow buffer; stores drain under MFMA
    if (h > hs) {
      const float* ob = orow + ((h - 1) & 1) * 8192;
#pragma unroll
      for (int s = 0; s < 2; ++s) {
        int pix = pixq + s * 8;
        f32x4 y = *(const f32x4*)(ob + pix * 512 + c4);
        f32x4 o;
        o[0] = fmaxf(y[0] + bias4[0], 0.f);
        o[1] = fmaxf(y[1] + bias4[1], 0.f);
        o[2] = fmaxf(y[2] + bias4[2], 0.f);
        o[3] = fmaxf(y[3] + bias4[3], 0.f);
        *(f32x4*)(out + outb + (size_t)((h - 1) * 64 + w0 + pix) * 512 + c4) = o;
      }
    }

    // P1: MFMA over 9 taps; A-frag = 1 swizzled ds_read_b128 each
    f32x4 a0 = {0, 0, 0, 0}, a1 = {0, 0, 0, 0};
#pragma unroll
    for (int dh = 0; dh < 3; ++dh) {
      const char* sb = smem + ((h - 1 + dh) & 3) * SLOT_B;
#pragma unroll
      for (int dw = 0; dw < 3; ++dw) {
        int col = n16 + dw;
        int addr = (col * 1024 + gbase) ^ ((col & 7) << 4);
        bf16x8 a = *(const bf16x8*)(sb + addr);
        a0 = __builtin_amdgcn_mfma_f32_16x16x32_bf16(a, wf[dh * 3 + dw][0], a0, 0, 0, 0);
        a1 = __builtin_amdgcn_mfma_f32_16x16x32_bf16(a, wf[dh * 3 + dw][1], a1, 0, 0, 0);
      }
    }

    // P2: scatter D (n=lane&15, m=g4*4+rr) into this row's orow buffer
    float* oh = orow + (h & 1) * 8192;
#pragma unroll
    for (int rr = 0; rr < 4; ++rr) {
      int m = (g4 * 4 + rr) * 512;
      oh[m + opos0] = a0[rr];
      oh[m + opos1] = a1[rr];
    }
    __syncthreads();   // single barrier: orow visible, DMA h+2 drained, slot reuse safe
  }

  // epilogue: flush last row
  {
    const int h1 = hs + 15;
    const float* ob = orow + (h1 & 1) * 8192;
#pragma unroll
    for (int s = 0; s < 2; ++s) {
      int pix = pixq + s * 8;
      f32x4 y = *(const f32x4*)(ob + pix * 512 + c4);
      f32x4 o;
      o[0] = fmaxf(y[0] + bias4[0], 0.f);
      o[1] = fmaxf(y[1] + bias4[1], 0.f);
      o[2] = fmaxf(y[2] + bias4[2], 0.f);
      o[3] = fmaxf(y[3] + bias4[3], 0.f);
      *(f32x4*)(out + outb + (size_t)(h1 * 64 + w0 + pix) * 512 + c4) = o;
    }
  }
}

extern "C" void kernel_launch(void* const* d_in, const int* in_sizes, int n_in,
                              void* d_out, int out_size, void* d_ws, size_t ws_size,
                              hipStream_t stream) {
  const float* x    = (const float*)d_in[0];
  const float* wts  = (const float*)d_in[1];
  const float* bias = (const float*)d_in[2];
  const int*   bin  = (const int*)d_in[3];
  const int*   bout = (const int*)d_in[4];
  float* out = (float*)d_out;
  unsigned char* xs = (unsigned char*)d_ws;   // needs 64 MiB
  (void)in_sizes; (void)n_in; (void)out_size; (void)ws_size;

  permute_kernel<<<dim3(2048), dim3(256), 0, stream>>>(x, bin, xs);
  conv_kernel<<<dim3(256), dim3(1024), SMEM2, stream>>>(xs, wts, bias, bout, out);
}